// Round 11
// baseline (295.336 us; speedup 1.0000x reference)
//
#include <hip/hip_runtime.h>
#include <math.h>

// Problem dims: B=4, T=128, I=32, H=64 (compile-time)
// d_out float layout (reference return order):
// final_carry (4,64) | out (4,128,64) | J_Wi (4,128,64,32,64) | J_Wh (4,128,64,64,64)
// | J_b (4,128,64,64) | J_h (4,128,64,4,64)
#define OFF_OUT   256u
#define OFF_JWI   33024u
#define OFF_JWH   67141888u
#define OFF_JB    201359616u
#define OFF_JH    203456768u

typedef float f32x4 __attribute__((ext_vector_type(4)));

static __device__ __forceinline__ float tanh_fast(float x) {
    // tanh(x) = 1 - 2/(e^{2x}+1); exact limits, ~1e-6 rel error
    float t = __expf(2.0f * x);
    return 1.0f - 2.0f / (t + 1.0f);
}

// ---------------------------------------------------------------------------
// Kernel 1: u[bt,j] = b[j] + sum_i x[bt,i]*Wi[i,j], staged INTO the `out`
// region (scan overwrites with a). 128 blocks x 256 threads.
// ---------------------------------------------------------------------------
__global__ __launch_bounds__(256) void xwi_kernel(
    const float* __restrict__ x, const float* __restrict__ Wi,
    const float* __restrict__ bias, float* __restrict__ out)
{
    const int tid = threadIdx.x;
    const int row = blockIdx.x * 4 + (tid >> 6);   // bt in [0,512)
    const int j = tid & 63;
    const float* xr = x + row * 32;
    float acc = bias[j];
#pragma unroll
    for (int i = 0; i < 32; ++i) acc = fmaf(xr[i], Wi[i * 64 + j], acc);
    out[OFF_OUT + row * 64 + j] = acc;
}

// ---------------------------------------------------------------------------
// Kernel 2: sequential scan. 4 blocks (1 wave each), block = batch.
// Depth-2 global u prefetch; Wh column j in 64 VGPRs; same-wave LDS h
// exchange (no barriers). Materializes hprev[bt*64+m] (h entering step t)
// into d_ws for the fill kernel's J_Wh diag phase.
// ---------------------------------------------------------------------------
__global__ __launch_bounds__(64) void scan_kernel(
    const float* __restrict__ carry, const float* __restrict__ Wh,
    float* __restrict__ out, float* __restrict__ hprev)
{
    const int b = blockIdx.x;
    const int j = threadIdx.x;
    float wcol[64];
#pragma unroll
    for (int m = 0; m < 64; ++m) wcol[m] = Wh[m * 64 + j];

    __shared__ __align__(16) float sh[64];
    float a_prev = carry[b * 64 + j];
    sh[j] = a_prev;
    float* ub = out + OFF_OUT + b * 8192;          // u in, a out (in place)
    float* hb = hprev + b * 8192;
    float u0 = ub[j];
    float u1 = ub[64 + j];
    const f32x4* shv = reinterpret_cast<const f32x4*>(sh);
    float a = 0.0f;

    for (int t = 0; t < 128; ++t) {
        hb[t * 64 + j] = a_prev;                   // h entering step t
        const float pre = u0;
        u0 = u1;
        if (t + 2 < 128) u1 = ub[(t + 2) * 64 + j];
        float s0 = 0.f, s1 = 0.f, s2 = 0.f, s3 = 0.f;
#pragma unroll
        for (int mm = 0; mm < 16; ++mm) {
            const f32x4 hv = shv[mm];              // lane-uniform broadcast
            s0 = fmaf(hv.x, wcol[mm * 4 + 0], s0);
            s1 = fmaf(hv.y, wcol[mm * 4 + 1], s1);
            s2 = fmaf(hv.z, wcol[mm * 4 + 2], s2);
            s3 = fmaf(hv.w, wcol[mm * 4 + 3], s3);
        }
        a = tanh_fast(pre + (s0 + s1) + (s2 + s3));
        ub[t * 64 + j] = a;
        sh[j] = a;                                 // same-wave LDS exchange
        a_prev = a;
    }
    out[b * 64 + j] = a;                           // final carry
}

// ---------------------------------------------------------------------------
// Kernel 3: single-touch L2-merged fill. One block per 256KB slab.
// Phase A: zero the slab with PLAIN full-line f32x4 stores (memset pattern,
//          lines become dirty in this XCD's L2).
// Phase B: overwrite the ~1024 diag float4s (or dense J_h rows) with PLAIN
//          16B stores -> guaranteed L2 hits (slab still resident) -> lines
//          merge and drain to HBM exactly ONCE.
//   blk [0,2048):     J_Wh  slab = (bt, j-quarter)
//   blk [2048,3072):  J_Wi  slab = (bt, j-half)
//   blk [3072,3104):  J_b   slab = 1024 rows
//   blk [3104,3232):  J_h   slab = 4 bt-slabs
// ---------------------------------------------------------------------------
__global__ __launch_bounds__(256) void fill_kernel(
    const float* __restrict__ x, const float* __restrict__ Wh,
    float* __restrict__ out, const float* __restrict__ hprev)
{
    const int tid = threadIdx.x;
    const unsigned blk = blockIdx.x;               // [0,3232)
    const float* __restrict__ outh = out + OFF_OUT;

    size_t base;
    if (blk < 2048u)      base = OFF_JWH + (size_t)blk * 65536u;
    else if (blk < 3072u) base = OFF_JWI + (size_t)(blk - 2048u) * 65536u;
    else if (blk < 3104u) base = OFF_JB  + (size_t)(blk - 3072u) * 65536u;
    else                  base = OFF_JH  + (size_t)(blk - 3104u) * 65536u;

    // ---- Phase A: plain full-line zero of the whole 256KB slab ----
    f32x4* s4 = reinterpret_cast<f32x4*>(out + base);
    const f32x4 z = {0.f, 0.f, 0.f, 0.f};
#pragma unroll 4
    for (int k = 0; k < 64; ++k)
        s4[k * 256 + tid] = z;
    __syncthreads();                               // all lines written (dirty in L2)

    // ---- Phase B: diag / dense payload (L2-hit merges) ----
    if (blk < 2048u) {
        // J_Wh slab (bt, jq): diag k=j; val = g[j] * hprev[bt,m]
        const unsigned bt = blk >> 2, jq = blk & 3u;
        const float* hb = hprev + bt * 64u;
#pragma unroll
        for (int k = 0; k < 4; ++k) {
            const unsigned p = tid + k * 256u;     // (j_loc, m) pair
            const unsigned jl = p >> 6, m = p & 63u;
            const unsigned jg = jq * 16u + jl;
            const float a = outh[bt * 64u + jg];
            const float v = (1.0f - a * a) * hb[m];
            const unsigned d = jg & 3u;
            f32x4 r = { d == 0u ? v : 0.f, d == 1u ? v : 0.f,
                        d == 2u ? v : 0.f, d == 3u ? v : 0.f };
            *reinterpret_cast<f32x4*>(out + base + (size_t)p * 64u + (jg & ~3u)) = r;
        }
    } else if (blk < 3072u) {
        // J_Wi slab (bt, jh): diag k=j; val = g[j] * x[bt,i]
        const unsigned idx = blk - 2048u;
        const unsigned bt = idx >> 1, jh = idx & 1u;
#pragma unroll
        for (int k = 0; k < 4; ++k) {
            const unsigned p = tid + k * 256u;     // (j_loc, i) pair
            const unsigned jl = p >> 5, i = p & 31u;
            const unsigned jg = jh * 32u + jl;
            const float a = outh[bt * 64u + jg];
            const float v = (1.0f - a * a) * x[bt * 32u + i];
            const unsigned d = jg & 3u;
            f32x4 r = { d == 0u ? v : 0.f, d == 1u ? v : 0.f,
                        d == 2u ? v : 0.f, d == 3u ? v : 0.f };
            *reinterpret_cast<f32x4*>(out + base + (size_t)p * 64u + (jg & ~3u)) = r;
        }
    } else if (blk < 3104u) {
        // J_b slab: diag k=j per row; val = g
        const unsigned c = blk - 3072u;
#pragma unroll
        for (int k = 0; k < 4; ++k) {
            const unsigned pl = tid + k * 256u;    // local row
            const unsigned j = pl & 63u;
            const float a = outh[c * 1024u + pl];
            const float g = 1.0f - a * a;
            const unsigned d = j & 3u;
            f32x4 r = { d == 0u ? g : 0.f, d == 1u ? g : 0.f,
                        d == 2u ? g : 0.f, d == 3u ? g : 0.f };
            *reinterpret_cast<f32x4*>(out + base + (size_t)pl * 64u + (j & ~3u)) = r;
        }
    } else {
        // J_h slab q: dense rows at c==b; val = g[s,j] * Wh[m,j]
        const unsigned q = blk - 3104u;
        const unsigned b = (q * 4u) >> 7;          // uniform per slab
        const unsigned m0 = (tid & 15u) * 4u;
#pragma unroll 4
        for (int k = 0; k < 16; ++k) {
            const unsigned rr = (tid >> 4) + k * 16u;   // row = s*64+j in [0,256)
            const unsigned s = rr >> 6, j = rr & 63u;
            const float a = outh[(q * 4u + s) * 64u + j];
            const float g = 1.0f - a * a;
            f32x4 r = { g * Wh[(m0 + 0u) * 64u + j], g * Wh[(m0 + 1u) * 64u + j],
                        g * Wh[(m0 + 2u) * 64u + j], g * Wh[(m0 + 3u) * 64u + j] };
            *reinterpret_cast<f32x4*>(
                out + base + ((size_t)rr * 4u + b) * 64u + m0) = r;
        }
    }
}

extern "C" void kernel_launch(void* const* d_in, const int* in_sizes, int n_in,
                              void* d_out, int out_size, void* d_ws, size_t ws_size,
                              hipStream_t stream) {
    const float* carry = (const float*)d_in[0];
    const float* x     = (const float*)d_in[1];
    const float* Wi    = (const float*)d_in[2];
    const float* Wh    = (const float*)d_in[3];
    const float* bias  = (const float*)d_in[4];
    float* out = (float*)d_out;
    float* hprev = (float*)d_ws;                   // 32768 floats (128 KB)

    xwi_kernel <<<128, 256, 0, stream>>>(x, Wi, bias, out);
    scan_kernel<<<4, 64, 0, stream>>>(carry, Wh, out, hprev);
    fill_kernel<<<3232, 256, 0, stream>>>(x, Wh, out, hprev);
}

// Round 12
// 182.367 us; speedup vs baseline: 1.6195x; 1.6195x over previous
//
#include <hip/hip_runtime.h>
#include <math.h>

// Problem dims: B=4, T=128, I=32, H=64 (compile-time)
// d_out float layout (reference return order):
// final_carry (4,64) | out (4,128,64) | J_Wi (4,128,64,32,64) | J_Wh (4,128,64,64,64)
// | J_b (4,128,64,64) | J_h (4,128,64,4,64)
#define OFF_OUT   256u
#define OFF_JWI   33024u
#define OFF_JWH   67141888u
#define OFF_JB    201359616u
#define OFF_JH    203456768u

typedef float f32x4 __attribute__((ext_vector_type(4)));

static __device__ __forceinline__ float tanh_fast(float x) {
    // tanh(x) = 1 - 2/(e^{2x}+1); exact limits, ~1e-6 rel error
    float t = __expf(2.0f * x);
    return 1.0f - 2.0f / (t + 1.0f);
}

// ---------------------------------------------------------------------------
// Kernel 1: u[bt,j] = b[j] + sum_i x[bt,i]*Wi[i,j]  (staged at start of J_b
// region; diag pass overwrites it afterwards). 128 blocks x 256 threads.
// ---------------------------------------------------------------------------
__global__ __launch_bounds__(256) void xwi_kernel(
    const float* __restrict__ x, const float* __restrict__ Wi,
    const float* __restrict__ bias, float* __restrict__ u)
{
    const int tid = threadIdx.x;
    const int row = blockIdx.x * 4 + (tid >> 6);   // bt in [0,512)
    const int j = tid & 63;
    const float* xr = x + row * 32;
    float acc = bias[j];
#pragma unroll
    for (int i = 0; i < 32; ++i) acc = fmaf(xr[i], Wi[i * 64 + j], acc);
    u[row * 64 + j] = acc;
}

// ---------------------------------------------------------------------------
// Kernel 2: block 0 = sequential scan (wave w = batch w, barrier-free).
// Blocks 1..512 = zero-fill of structurally-zero half-lines, NT stores.
// LOW-STREAM-COUNT config: 2048 zero waves (8/CU), each wave writes 4
// CONSECUTIVE units (32 rows = 8KB span) per iteration -> few, long DRAM
// burst streams (memset-like) instead of ~8192 interleaved ones.
//   unit < 131072:  J_Wi non-diag 128B half-lines (unit = 8 rows)
//   unit < 393216:  J_Wh non-diag 128B half-lines (unit = 8 rows)
//   else         :  J_h flat memset (unit = 256 floats)
// ---------------------------------------------------------------------------
__global__ __launch_bounds__(256) void scan_zero_kernel(
    const float* __restrict__ carry, const float* __restrict__ u,
    const float* __restrict__ Wh, float* __restrict__ out)
{
    const int tid = threadIdx.x;
    if (blockIdx.x == 0) {
        const int w = tid >> 6, j = tid & 63;
        float wcol[64];
#pragma unroll
        for (int m = 0; m < 64; ++m) wcol[m] = Wh[m * 64 + j];
        __shared__ __align__(16) float sh[256];
        sh[tid] = carry[tid];
        const float* ub = u + w * 8192;
        float* ob = out + OFF_OUT + w * 8192;
        const f32x4* shv = reinterpret_cast<const f32x4*>(sh + w * 64);
        float unext = ub[j];
        float a = 0.0f;
        for (int t = 0; t < 128; ++t) {
            const float pre = unext;
            if (t < 127) unext = ub[(t + 1) * 64 + j];
            float a0 = 0.f, a1 = 0.f, a2 = 0.f, a3 = 0.f;
#pragma unroll
            for (int mm = 0; mm < 16; ++mm) {
                const f32x4 hv = shv[mm];           // lane-uniform 16B read
                a0 = fmaf(hv.x, wcol[mm * 4 + 0], a0);
                a1 = fmaf(hv.y, wcol[mm * 4 + 1], a1);
                a2 = fmaf(hv.z, wcol[mm * 4 + 2], a2);
                a3 = fmaf(hv.w, wcol[mm * 4 + 3], a3);
            }
            a = tanh_fast(pre + (a0 + a1) + (a2 + a3));
            ob[t * 64 + j] = a;
            sh[tid] = a;                             // next iter reads it
        }
        out[tid] = a;                                // final carry
    } else {
        const unsigned NW = (gridDim.x - 1u) * 4u;   // 2048 waves
        const unsigned wid = (blockIdx.x - 1u) * 4u + (tid >> 6);
        const unsigned l = tid & 63u;
        const f32x4 z = {0.f, 0.f, 0.f, 0.f};
        for (unsigned base = wid * 4u; base < 425984u; base += NW * 4u) {
#pragma unroll
            for (unsigned k = 0; k < 4u; ++k) {
                const unsigned uu = base + k;        // consecutive -> 8KB burst
                unsigned addr;
                if (uu < 131072u) {
                    const unsigned r0 = uu * 8u;                 // J_Wi row
                    const unsigned j = (r0 >> 5) & 63u;          // uniform over 8 rows
                    addr = OFF_JWI + r0 * 64u + ((j < 32u) ? 32u : 0u)
                         + (l >> 3) * 64u + (l & 7u) * 4u;
                } else if (uu < 393216u) {
                    const unsigned r0 = (uu - 131072u) * 8u;     // J_Wh row
                    const unsigned j = (r0 >> 6) & 63u;
                    addr = OFF_JWH + r0 * 64u + ((j < 32u) ? 32u : 0u)
                         + (l >> 3) * 64u + (l & 7u) * 4u;
                } else {
                    addr = OFF_JH + (uu - 393216u) * 256u + l * 4u;
                }
                __builtin_nontemporal_store(z, reinterpret_cast<f32x4*>(out + addr));
            }
        }
    }
}

// ---------------------------------------------------------------------------
// Kernel 3: data-dependent fill (diag half-lines + dense J_h rows), NT
// stores, same low-stream-count scheduling (512 blocks, 4 consecutive
// units per wave-iteration).
//   unit < 131072:  J_Wi diag halves   (unit = 8 rows, 1 f32x4/lane)
//   unit < 393216:  J_Wh diag halves   (unit = 8 rows)
//   unit < 401408:  J_b full rows      (unit = 4 rows of 64 floats)
//   else         :  J_h c==b rows      (unit = 4 (bt,j) rows of 64 floats)
// ---------------------------------------------------------------------------
__global__ __launch_bounds__(256) void diag_fill_kernel(
    const float* __restrict__ carry, const float* __restrict__ x,
    const float* __restrict__ Wh, float* __restrict__ out)
{
    const int tid = threadIdx.x;
    const unsigned NW = gridDim.x * 4u;
    const unsigned wid = blockIdx.x * 4u + (tid >> 6);
    const unsigned l = tid & 63u;
    const float* __restrict__ outh = out + OFF_OUT;

    for (unsigned base = wid * 4u; base < 409600u; base += NW * 4u) {
#pragma unroll
        for (unsigned k = 0; k < 4u; ++k) {
            const unsigned uu = base + k;            // consecutive units
            unsigned addr;
            f32x4 r = {0.f, 0.f, 0.f, 0.f};
            if (uu < 131072u) {
                const unsigned r0 = uu * 8u;
                const unsigned bt = r0 >> 11;
                const unsigned j = (r0 >> 5) & 63u;
                const float a = outh[bt * 64u + j];          // wave-uniform
                const float g = 1.0f - a * a;
                const unsigned i = (r0 + (l >> 3)) & 31u;
                const float v = g * x[bt * 32u + i];
                const unsigned d = (j & 31u) - (l & 7u) * 4u;
                r.x = (d == 0u) ? v : 0.f; r.y = (d == 1u) ? v : 0.f;
                r.z = (d == 2u) ? v : 0.f; r.w = (d == 3u) ? v : 0.f;
                addr = OFF_JWI + r0 * 64u + ((j < 32u) ? 0u : 32u)
                     + (l >> 3) * 64u + (l & 7u) * 4u;
            } else if (uu < 393216u) {
                const unsigned r0 = (uu - 131072u) * 8u;
                const unsigned bt = r0 >> 12;
                const unsigned j = (r0 >> 6) & 63u;
                const unsigned t = bt & 127u, b = bt >> 7;
                const float a = outh[bt * 64u + j];
                const float g = 1.0f - a * a;
                const unsigned m = (r0 + (l >> 3)) & 63u;
                const float hv = (t == 0u) ? carry[b * 64u + m]
                                           : outh[(bt - 1u) * 64u + m];
                const float v = g * hv;
                const unsigned d = (j & 31u) - (l & 7u) * 4u;
                r.x = (d == 0u) ? v : 0.f; r.y = (d == 1u) ? v : 0.f;
                r.z = (d == 2u) ? v : 0.f; r.w = (d == 3u) ? v : 0.f;
                addr = OFF_JWH + r0 * 64u + ((j < 32u) ? 0u : 32u)
                     + (l >> 3) * 64u + (l & 7u) * 4u;
            } else if (uu < 401408u) {
                const unsigned p = (uu - 393216u) * 4u + (l >> 4);  // bt*64+j
                const unsigned j = p & 63u;
                const float a = outh[p];
                const float g = 1.0f - a * a;
                const unsigned d = j - (l & 15u) * 4u;
                r.x = (d == 0u) ? g : 0.f; r.y = (d == 1u) ? g : 0.f;
                r.z = (d == 2u) ? g : 0.f; r.w = (d == 3u) ? g : 0.f;
                addr = OFF_JB + p * 64u + (l & 15u) * 4u;
            } else {
                const unsigned p = (uu - 401408u) * 4u + (l >> 4);  // bt*64+j
                const unsigned bt = p >> 6, j = p & 63u, b = bt >> 7;
                const float a = outh[p];
                const float g = 1.0f - a * a;
                const unsigned k0 = (l & 15u) * 4u;
                r.x = g * Wh[(k0 + 0u) * 64u + j];
                r.y = g * Wh[(k0 + 1u) * 64u + j];
                r.z = g * Wh[(k0 + 2u) * 64u + j];
                r.w = g * Wh[(k0 + 3u) * 64u + j];
                addr = OFF_JH + p * 256u + b * 64u + k0;
            }
            __builtin_nontemporal_store(r, reinterpret_cast<f32x4*>(out + addr));
        }
    }
}

extern "C" void kernel_launch(void* const* d_in, const int* in_sizes, int n_in,
                              void* d_out, int out_size, void* d_ws, size_t ws_size,
                              hipStream_t stream) {
    const float* carry = (const float*)d_in[0];
    const float* x     = (const float*)d_in[1];
    const float* Wi    = (const float*)d_in[2];
    const float* Wh    = (const float*)d_in[3];
    const float* bias  = (const float*)d_in[4];
    float* out = (float*)d_out;
    float* u = out + OFF_JB;   // staging; overwritten by diag_fill_kernel

    xwi_kernel      <<<128, 256, 0, stream>>>(x, Wi, bias, u);
    scan_zero_kernel<<<513, 256, 0, stream>>>(carry, u, Wh, out);
    diag_fill_kernel<<<512, 256, 0, stream>>>(carry, x, Wh, out);
}